// Round 9
// baseline (599.620 us; speedup 1.0000x reference)
//
#include <hip/hip_runtime.h>
#include <hip/hip_bf16.h>

// (B,T,D,H) = (4,2048,384,6), HD=64. Inputs/output f32; intermediates bf16.
#define BB   4
#define TT   2048
#define DDIM 384
#define HH   6
#define HD   64
#define BT   (BB*TT)
#define QKVC (3*DDIM)
#define NBLK 768          // 256 CU x 3 blocks/CU — exact co-residency

#define QSCALE 0.18033688011112042f   // 0.125 * log2(e), folded into Q at RoPE
#define LOG2E  1.4426950408889634f

typedef __attribute__((ext_vector_type(4))) short short4v;
typedef __attribute__((ext_vector_type(8))) short short8v;
typedef __attribute__((ext_vector_type(4))) float float4v;
typedef unsigned short u16;

static __device__ __forceinline__ u16 f2bu(float f) {
    __hip_bfloat16 h = __float2bfloat16(f);
    return __builtin_bit_cast(u16, h);
}
static __device__ __forceinline__ unsigned pk2(float lo, float hi) {
    return (unsigned)f2bu(lo) | ((unsigned)f2bu(hi) << 16);   // v_cvt_pk_bf16_f32
}
static __device__ __forceinline__ short8v frag4(uint4 v) {
    return __builtin_bit_cast(short8v, v);
}
static __device__ __forceinline__ short8v ld_frag(const u16* p) {
    short4v a = *(const short4v*)p;     // 2x b64: safe for 8B-aligned rows
    short4v b = *(const short4v*)(p + 4);
    return __builtin_shufflevector(a, b, 0, 1, 2, 3, 4, 5, 6, 7);
}
static __device__ __forceinline__ void st8(u16* p, uint4 v) {
    *(uint2*)p       = make_uint2(v.x, v.y);
    *(uint2*)(p + 4) = make_uint2(v.z, v.w);
}
// permlane swaps (gfx950) — P C-layout -> A-layout redistribution (verified r2)
static __device__ __forceinline__ void pl32swap(unsigned &a, unsigned &b) {
    auto r = __builtin_amdgcn_permlane32_swap(a, b, false, false);
    a = r[0]; b = r[1];
}
static __device__ __forceinline__ void pl16swap(unsigned &a, unsigned &b) {
    auto r = __builtin_amdgcn_permlane16_swap(a, b, false, false);
    a = r[0]; b = r[1];
}

#define MFMA16(a, b, c) __builtin_amdgcn_mfma_f32_16x16x32_bf16((a), (b), (c), 0, 0, 0)

// Device-scope grid barrier (G16: agent-scope acq_rel -> L2 wb/inv across XCDs).
// __syncthreads drains this block's vmcnt before t0 signals; release orders the
// block's prior global writes; acquire invalidates this XCD's caches.
static __device__ __forceinline__ void grid_barrier(unsigned* bar, int t) {
    __syncthreads();
    if (t == 0) {
        __hip_atomic_fetch_add(bar, 1u, __ATOMIC_ACQ_REL, __HIP_MEMORY_SCOPE_AGENT);
        unsigned v;
        do {
            __builtin_amdgcn_s_sleep(2);
            v = __hip_atomic_load(bar, __ATOMIC_ACQUIRE, __HIP_MEMORY_SCOPE_AGENT);
        } while (v < NBLK);
    }
    __syncthreads();
}

// stage ws[c][k] = bf16(w[k][c0+c]) for c<64, k<384 (w row stride C).
static __device__ __forceinline__ void stage_wT(
    u16 (*ws)[392], const float* __restrict__ w, int C, int c0, int t)
{
    const int c = t & 63;
    const int kb0 = t >> 6;
    #pragma unroll
    for (int u = 0; u < 12; ++u) {
        int k = (kb0 + 4 * u) * 8;
        const float* wp = w + (size_t)k * C + c0 + c;
        float v0 = wp[0];
        float v1 = wp[(size_t)1 * C];
        float v2 = wp[(size_t)2 * C];
        float v3 = wp[(size_t)3 * C];
        float v4 = wp[(size_t)4 * C];
        float v5 = wp[(size_t)5 * C];
        float v6 = wp[(size_t)6 * C];
        float v7 = wp[(size_t)7 * C];
        uint4 pv = make_uint4(pk2(v0, v1), pk2(v2, v3), pk2(v4, v5), pk2(v6, v7));
        *(uint4*)&ws[c][k] = pv;
    }
}

// ---------------------------------------------------------------------------
// THE kernel: persistent 768 blocks, 3 phases, 2 device-scope grid barriers.
//  P1: qkv = x @ wqkv^T + RoPE (2304 tiles, grid-stride) + bias zero-check
//  P2: attention (768 tiles; K-split fast path / bias fallback on flag)
//  P3: out = O @ w_proj (768 tiles)
// ---------------------------------------------------------------------------
__global__ __launch_bounds__(256, 3) void fused_mhsa_kernel(
    const float* __restrict__ x, const float* __restrict__ wqkv,
    const float* __restrict__ wproj, const float* __restrict__ bias,
    const float* __restrict__ cs, const float* __restrict__ sn,
    u16* __restrict__ qb, u16* __restrict__ kb, u16* __restrict__ vtb,
    u16* __restrict__ ob, float* __restrict__ out,
    unsigned* __restrict__ sync)   // sync[0]=flag, [1]=bar1, [2]=bar2
{
    __shared__ __align__(16) u16 smem[25088];   // 50176 B union
    const int t = threadIdx.x;
    const int blk = blockIdx.x;
    const int wv = t >> 6, lane = t & 63, quad = lane >> 4, lo = lane & 15;

    // ================= Phase 1: bias-check + qkv+RoPE =================
    for (int it = blk; it < 3328; it += NBLK) {
        if (it < 1024) {               // bias nonzero check, chunk `it`
            const float* gp = bias + (size_t)it * 4096 + (size_t)t * 16;
            unsigned acc = 0;
            #pragma unroll
            for (int u = 0; u < 4; ++u) {
                float4 v = *(const float4*)(gp + 4 * u);
                acc |= (__builtin_bit_cast(unsigned, v.x) & 0x7fffffffu);
                acc |= (__builtin_bit_cast(unsigned, v.y) & 0x7fffffffu);
                acc |= (__builtin_bit_cast(unsigned, v.z) & 0x7fffffffu);
                acc |= (__builtin_bit_cast(unsigned, v.w) & 0x7fffffffu);
            }
            if (acc) atomicOr(sync, 1u);
            continue;
        }
        const int qid = it - 1024;     // 0..2303
        const int c0 = (qid % 18) * 64;
        const int r0 = (qid / 18) * 64;
        u16 (*ws)[392] = (u16(*)[392])smem;

        __syncthreads();               // WAR: ws reuse across loop iterations
        stage_wT(ws, wqkv, QKVC, c0, t);

        // A fragments: x row (f32) -> bf16 in-register, full K
        const float* arow = x + (size_t)(r0 + 16 * wv + lo) * DDIM + quad * 8;
        uint4 af[12];
        #pragma unroll
        for (int kf = 0; kf < 12; ++kf) {
            float4 a0 = *(const float4*)(arow + kf * 32);
            float4 a1 = *(const float4*)(arow + kf * 32 + 4);
            af[kf] = make_uint4(pk2(a0.x, a0.y), pk2(a0.z, a0.w),
                                pk2(a1.x, a1.y), pk2(a1.z, a1.w));
        }
        __syncthreads();

        float4v acc[4] = {};
        #pragma unroll
        for (int kf = 0; kf < 12; ++kf) {
            short8v a = frag4(af[kf]);
            #pragma unroll
            for (int nt = 0; nt < 4; ++nt) {
                short8v b = ld_frag(&ws[nt * 16 + lo][kf * 32 + quad * 8]);
                acc[nt] = MFMA16(a, b, acc[nt]);
            }
        }

        const int cb = qid % 18;
        const int sec = cb / 6;        // 0=q, 1=k, 2=v
        const int h   = cb % 6;
        const int rbase = r0 + 16 * wv + 4 * quad;
        const int bidx  = r0 >> 11;
        const int tbase = rbase & (TT - 1);

        if (sec == 2) {
            #pragma unroll
            for (int nt = 0; nt < 4; ++nt) {
                int d = nt * 16 + lo;
                unsigned a0 = pk2(acc[nt][0], acc[nt][1]);
                unsigned a1 = pk2(acc[nt][2], acc[nt][3]);
                u16* gp = vtb + ((size_t)(bidx * HH + h) * HD + d) * TT + tbase;
                *(uint2*)gp = make_uint2(a0, a1);
            }
        } else {
            u16* dst = (sec == 0) ? qb : kb;
            const float scl = (sec == 0) ? QSCALE : 1.0f;
            #pragma unroll
            for (int np = 0; np < 2; ++np) {
                #pragma unroll
                for (int r = 0; r < 4; ++r) {
                    int tpos = tbase + r;
                    int ci = np * 16 + lo;
                    float cv = cs[tpos * 32 + ci];
                    float sv = sn[tpos * 32 + ci];
                    float x1 = acc[np][r], x2 = acc[np + 2][r];
                    u16* gp = dst + ((size_t)(bidx * HH + h) * TT + tpos) * HD;
                    gp[ci]      = f2bu((x1 * cv - x2 * sv) * scl);
                    gp[ci + 32] = f2bu((x2 * cv + x1 * sv) * scl);
                }
            }
        }
    }

    grid_barrier(sync + 1, t);

    // ================= Phase 2: attention (1 tile per block) =================
    {
        const int bh = blk % 24;       // XCD pinning: blk%8 == bh%8
        const int b = bh / HH, h = bh % HH;
        const int q0 = (blk / 24) * 64;

        if (sync[0] == 0u) {
            // ------------- K-split fast path (zero bias) -------------
            float* red_o = (float*)smem;                 // [2][64][68] floats
            float* red_l = (float*)(smem + 17408);       // [4][64] floats

            short8v aq[4][2];
            #pragma unroll
            for (int g = 0; g < 4; ++g) {
                const u16* qp = qb + ((size_t)bh * TT + q0 + g * 16 + lo) * HD + quad * 8;
                aq[g][0] = frag4(*(const uint4*)qp);
                aq[g][1] = frag4(*(const uint4*)(qp + 32));
            }

            const u16* kbase = kb + ((size_t)bh * TT + lo) * HD + quad * 8;
            const u16* vbase = vtb + ((size_t)bh * HD + lo) * TT + quad * 8;

            uint4 kq[4][2], vq[4][2];
            {
                const size_t ko = (size_t)wv * 64 * HD;
                const size_t vo = (size_t)wv * 64;
                #pragma unroll
                for (int nt = 0; nt < 4; ++nt) {
                    kq[nt][0] = *(const uint4*)(kbase + ko + (size_t)nt * 16 * HD);
                    kq[nt][1] = *(const uint4*)(kbase + ko + (size_t)nt * 16 * HD + 32);
                }
                #pragma unroll
                for (int dt = 0; dt < 4; ++dt) {
                    vq[dt][0] = *(const uint4*)(vbase + (size_t)dt * 16 * TT + vo);
                    vq[dt][1] = *(const uint4*)(vbase + (size_t)dt * 16 * TT + vo + 32);
                }
            }

            float4v oacc[4][4] = {};
            float lacc[4] = {0.f, 0.f, 0.f, 0.f};

            for (int j = 0; j < 8; ++j) {
                const int ktn = (j < 7) ? (wv + 4 * (j + 1)) : wv;
                const size_t kno = (size_t)ktn * 64 * HD;
                const size_t vno = (size_t)ktn * 64;

                #pragma unroll
                for (int g = 0; g < 4; ++g) {
                    float4v s[4] = {};
                    #pragma unroll
                    for (int nt = 0; nt < 4; ++nt)
                        s[nt] = MFMA16(frag4(kq[nt][0]), aq[g][0], s[nt]);
                    #pragma unroll
                    for (int nt = 0; nt < 4; ++nt)
                        s[nt] = MFMA16(frag4(kq[nt][1]), aq[g][1], s[nt]);
                    if (g == 3) {
                        #pragma unroll
                        for (int nt = 0; nt < 4; ++nt) {
                            kq[nt][0] = *(const uint4*)(kbase + kno + (size_t)nt * 16 * HD);
                            kq[nt][1] = *(const uint4*)(kbase + kno + (size_t)nt * 16 * HD + 32);
                        }
                    }

                    unsigned w[8];
                    #pragma unroll
                    for (int nt = 0; nt < 4; ++nt) {
                        float p0 = __builtin_amdgcn_exp2f(s[nt][0]);
                        float p1 = __builtin_amdgcn_exp2f(s[nt][1]);
                        float p2 = __builtin_amdgcn_exp2f(s[nt][2]);
                        float p3 = __builtin_amdgcn_exp2f(s[nt][3]);
                        lacc[g] += (p0 + p1) + (p2 + p3);
                        w[2 * nt]     = pk2(p0, p1);
                        w[2 * nt + 1] = pk2(p2, p3);
                    }

                    pl32swap(w[0], w[2]); pl16swap(w[0], w[2]);
                    pl32swap(w[1], w[3]); pl16swap(w[1], w[3]);
                    pl32swap(w[4], w[6]); pl16swap(w[4], w[6]);
                    pl32swap(w[5], w[7]); pl16swap(w[5], w[7]);
                    short8v pa0 = frag4(make_uint4(w[0], w[1], w[2], w[3]));
                    short8v pa1 = frag4(make_uint4(w[4], w[5], w[6], w[7]));

                    #pragma unroll
                    for (int dt = 0; dt < 4; ++dt)
                        oacc[g][dt] = MFMA16(pa0, frag4(vq[dt][0]), oacc[g][dt]);
                    #pragma unroll
                    for (int dt = 0; dt < 4; ++dt)
                        oacc[g][dt] = MFMA16(pa1, frag4(vq[dt][1]), oacc[g][dt]);
                    if (g == 3) {
                        #pragma unroll
                        for (int dt = 0; dt < 4; ++dt) {
                            vq[dt][0] = *(const uint4*)(vbase + (size_t)dt * 16 * TT + vno);
                            vq[dt][1] = *(const uint4*)(vbase + (size_t)dt * 16 * TT + vno + 32);
                        }
                    }
                }
            }

            #pragma unroll
            for (int g = 0; g < 4; ++g) {
                lacc[g] += __shfl_xor(lacc[g], 16);
                lacc[g] += __shfl_xor(lacc[g], 32);
            }
            if (quad == 0) {
                #pragma unroll
                for (int g = 0; g < 4; ++g) red_l[wv * 64 + g * 16 + lo] = lacc[g];
            }
            float* slot0 = red_o + (size_t)lane * 68;
            float* slot1 = red_o + 64 * 68 + (size_t)lane * 68;
            if (wv == 1 || wv == 3) {
                float* sp = (wv == 1) ? slot0 : slot1;
                #pragma unroll
                for (int g = 0; g < 4; ++g)
                    #pragma unroll
                    for (int dt = 0; dt < 4; ++dt)
                        *(float4v*)(sp + (g * 4 + dt) * 4) = oacc[g][dt];
            }
            __syncthreads();
            if (wv == 0 || wv == 2) {
                float* sp = (wv == 0) ? slot0 : slot1;
                #pragma unroll
                for (int g = 0; g < 4; ++g)
                    #pragma unroll
                    for (int dt = 0; dt < 4; ++dt)
                        oacc[g][dt] += *(const float4v*)(sp + (g * 4 + dt) * 4);
            }
            __syncthreads();
            if (wv == 2) {
                #pragma unroll
                for (int g = 0; g < 4; ++g)
                    #pragma unroll
                    for (int dt = 0; dt < 4; ++dt)
                        *(float4v*)(slot1 + (g * 4 + dt) * 4) = oacc[g][dt];
            }
            __syncthreads();
            if (wv == 0) {
                #pragma unroll
                for (int g = 0; g < 4; ++g) {
                    #pragma unroll
                    for (int dt = 0; dt < 4; ++dt)
                        oacc[g][dt] += *(const float4v*)(slot1 + (g * 4 + dt) * 4);
                    float lt = red_l[0 * 64 + g * 16 + lo] + red_l[1 * 64 + g * 16 + lo]
                             + red_l[2 * 64 + g * 16 + lo] + red_l[3 * 64 + g * 16 + lo];
                    #pragma unroll
                    for (int r = 0; r < 4; ++r) {
                        float lr = __shfl(lt, 4 * quad + r);
                        float inv = 1.f / lr;
                        u16* gp = ob + ((size_t)b * TT + q0 + g * 16 + 4 * quad + r) * DDIM
                                     + h * HD + lo;
                        #pragma unroll
                        for (int dt = 0; dt < 4; ++dt)
                            gp[dt * 16] = f2bu(oacc[g][dt][r] * inv);
                    }
                }
            }
        } else {
            // ------------- bias-nonzero fallback (LDS-staged) -------------
            typedef u16 (*lds_t)[64][68];
            lds_t ks = (lds_t)smem;                  // [2][64][68] u16 = 17408 B
            lds_t vt = (lds_t)(smem + 8704);         // next 17408 B (8704 u16)

            const int qrow = q0 + 16 * wv + lo;
            const u16* qbase = qb + ((size_t)bh * TT + qrow) * HD + quad * 8;
            short8v aq0 = frag4(*(const uint4*)qbase);
            short8v aq1 = frag4(*(const uint4*)(qbase + 32));

            const int sr = t >> 3, sd = (t & 7) * 8;
            const u16* kbbase = kb + (size_t)bh * TT * HD;
            const u16* vtbase = vtb + (size_t)bh * HD * TT;
            const float* brow = bias + (size_t)qrow * TT + 4 * quad;

            st8(&ks[0][sr][sd],      *(const uint4*)(kbbase + (size_t)sr * HD + sd));
            st8(&ks[0][sr + 32][sd], *(const uint4*)(kbbase + (size_t)(sr + 32) * HD + sd));
            st8(&vt[0][sr][sd],      *(const uint4*)(vtbase + (size_t)sr * TT + sd));
            st8(&vt[0][sr + 32][sd], *(const uint4*)(vtbase + (size_t)(sr + 32) * TT + sd));
            float4 bcur[4];
            #pragma unroll
            for (int nt = 0; nt < 4; ++nt) bcur[nt] = *(const float4*)(brow + nt * 16);
            __syncthreads();

            float4v oacc[4] = {};
            float lacc[4] = {0.f, 0.f, 0.f, 0.f};

            for (int kt = 0; kt < TT / 64; ++kt) {
                const int cur = kt & 1, nxt = cur ^ 1;
                const int kn = (kt < 31 ? kt + 1 : 31) * 64;

                uint4 kp0 = *(const uint4*)(kbbase + (size_t)(kn + sr) * HD + sd);
                uint4 kp1 = *(const uint4*)(kbbase + (size_t)(kn + sr + 32) * HD + sd);
                uint4 vp0 = *(const uint4*)(vtbase + (size_t)sr * TT + kn + sd);
                uint4 vp1 = *(const uint4*)(vtbase + (size_t)(sr + 32) * TT + kn + sd);
                float4 bnxt[4];
                #pragma unroll
                for (int nt = 0; nt < 4; ++nt)
                    bnxt[nt] = *(const float4*)(brow + kn + nt * 16);

                float4v s[4] = {};
                #pragma unroll
                for (int kf = 0; kf < 2; ++kf) {
                    #pragma unroll
                    for (int nt = 0; nt < 4; ++nt) {
                        short8v kfr = ld_frag(&ks[cur][nt * 16 + lo][kf * 32 + quad * 8]);
                        s[nt] = MFMA16(kfr, (kf ? aq1 : aq0), s[nt]);
                    }
                }

                unsigned w[8];
                #pragma unroll
                for (int nt = 0; nt < 4; ++nt) {
                    float p0 = __builtin_amdgcn_exp2f(fmaf(bcur[nt].x, LOG2E, s[nt][0]));
                    float p1 = __builtin_amdgcn_exp2f(fmaf(bcur[nt].y, LOG2E, s[nt][1]));
                    float p2 = __builtin_amdgcn_exp2f(fmaf(bcur[nt].z, LOG2E, s[nt][2]));
                    float p3 = __builtin_amdgcn_exp2f(fmaf(bcur[nt].w, LOG2E, s[nt][3]));
                    lacc[nt] += (p0 + p1) + (p2 + p3);
                    w[2 * nt]     = pk2(p0, p1);
                    w[2 * nt + 1] = pk2(p2, p3);
                }

                pl32swap(w[0], w[2]); pl16swap(w[0], w[2]);
                pl32swap(w[1], w[3]); pl16swap(w[1], w[3]);
                pl32swap(w[4], w[6]); pl16swap(w[4], w[6]);
                pl32swap(w[5], w[7]); pl16swap(w[5], w[7]);
                short8v pa0 = frag4(make_uint4(w[0], w[1], w[2], w[3]));
                short8v pa1 = frag4(make_uint4(w[4], w[5], w[6], w[7]));

                #pragma unroll
                for (int kf = 0; kf < 2; ++kf) {
                    #pragma unroll
                    for (int dt = 0; dt < 4; ++dt) {
                        short8v bv = ld_frag(&vt[cur][dt * 16 + lo][kf * 32 + quad * 8]);
                        oacc[dt] = MFMA16((kf ? pa1 : pa0), bv, oacc[dt]);
                    }
                }

                st8(&ks[nxt][sr][sd], kp0);
                st8(&ks[nxt][sr + 32][sd], kp1);
                st8(&vt[nxt][sr][sd], vp0);
                st8(&vt[nxt][sr + 32][sd], vp1);
                #pragma unroll
                for (int nt = 0; nt < 4; ++nt) bcur[nt] = bnxt[nt];
                __syncthreads();
            }

            float l = (lacc[0] + lacc[1]) + (lacc[2] + lacc[3]);
            l += __shfl_xor(l, 16);
            l += __shfl_xor(l, 32);
            #pragma unroll
            for (int r = 0; r < 4; ++r) {
                float lr = __shfl(l, 4 * quad + r);
                float inv = 1.f / lr;
                u16* gp = ob + ((size_t)b * TT + q0 + 16 * wv + 4 * quad + r) * DDIM
                             + h * HD + lo;
                #pragma unroll
                for (int dt = 0; dt < 4; ++dt)
                    gp[dt * 16] = f2bu(oacc[dt][r] * inv);
            }
        }
    }

    grid_barrier(sync + 2, t);

    // ================= Phase 3: out = O @ w_proj (1 tile per block) =========
    {
        const int c0 = (blk % 6) * 64;
        const int r0 = (blk / 6) * 64;
        u16 (*ws)[392] = (u16(*)[392])smem;

        stage_wT(ws, wproj, DDIM, c0, t);

        const u16* arow = ob + (size_t)(r0 + 16 * wv + lo) * DDIM + quad * 8;
        uint4 af[12];
        #pragma unroll
        for (int kf = 0; kf < 12; ++kf)
            af[kf] = *(const uint4*)(arow + kf * 32);
        __syncthreads();

        float4v acc[4] = {};
        #pragma unroll
        for (int kf = 0; kf < 12; ++kf) {
            short8v a = frag4(af[kf]);
            #pragma unroll
            for (int nt = 0; nt < 4; ++nt) {
                short8v b = ld_frag(&ws[nt * 16 + lo][kf * 32 + quad * 8]);
                acc[nt] = MFMA16(a, b, acc[nt]);
            }
        }
        #pragma unroll
        for (int r = 0; r < 4; ++r) {
            float* gp = out + (size_t)(r0 + 16 * wv + 4 * quad + r) * DDIM + c0;
            #pragma unroll
            for (int nt = 0; nt < 4; ++nt)
                gp[nt * 16 + lo] = acc[nt][r];
        }
    }
}

extern "C" void kernel_launch(void* const* d_in, const int* in_sizes, int n_in,
                              void* d_out, int out_size, void* d_ws, size_t ws_size,
                              hipStream_t stream) {
    const float* x     = (const float*)d_in[0];
    const float* bias  = (const float*)d_in[1];
    const float* cs    = (const float*)d_in[2];
    const float* sn    = (const float*)d_in[3];
    const float* wqkv  = (const float*)d_in[4];
    const float* wproj = (const float*)d_in[5];
    float* out = (float*)d_out;

    u16* qb  = (u16*)d_ws;                            // [bh][t][d]
    u16* kb  = qb + (size_t)BB * HH * TT * HD;        // [bh][t][d]
    u16* vtb = kb + (size_t)BB * HH * TT * HD;        // [bh][d][t]
    u16* ob  = vtb + (size_t)BB * HH * TT * HD;       // [b][t][h*64+d]
    unsigned* sync = (unsigned*)(ob + (size_t)BT * DDIM);  // flag, bar1, bar2

    hipMemsetAsync(sync, 0, 3 * sizeof(unsigned), stream);
    fused_mhsa_kernel<<<NBLK, 256, 0, stream>>>(
        x, wqkv, wproj, bias, cs, sn, qb, kb, vtb, ob, out, sync);
}

// Round 10
// 167.499 us; speedup vs baseline: 3.5799x; 3.5799x over previous
//
#include <hip/hip_runtime.h>
#include <hip/hip_bf16.h>

// (B,T,D,H) = (4,2048,384,6), HD=64. Inputs/output f32; intermediates bf16.
#define BB   4
#define TT   2048
#define DDIM 384
#define HH   6
#define HD   64
#define BT   (BB*TT)
#define QKVC (3*DDIM)

#define QSCALE 0.18033688011112042f   // 0.125 * log2(e), folded into Q at RoPE
#define LOG2E  1.4426950408889634f

typedef __attribute__((ext_vector_type(4))) short short4v;
typedef __attribute__((ext_vector_type(8))) short short8v;
typedef __attribute__((ext_vector_type(4))) float float4v;
typedef unsigned short u16;

static __device__ __forceinline__ u16 f2bu(float f) {
    __hip_bfloat16 h = __float2bfloat16(f);
    return __builtin_bit_cast(u16, h);
}
static __device__ __forceinline__ unsigned pk2(float lo, float hi) {
    return (unsigned)f2bu(lo) | ((unsigned)f2bu(hi) << 16);   // v_cvt_pk_bf16_f32
}
static __device__ __forceinline__ short8v frag4(uint4 v) {
    return __builtin_bit_cast(short8v, v);
}
static __device__ __forceinline__ short8v ld_frag(const u16* p) {
    short4v a = *(const short4v*)p;     // 2x b64: safe for 8B-aligned rows
    short4v b = *(const short4v*)(p + 4);
    return __builtin_shufflevector(a, b, 0, 1, 2, 3, 4, 5, 6, 7);
}
static __device__ __forceinline__ void st8(u16* p, uint4 v) {
    *(uint2*)p       = make_uint2(v.x, v.y);
    *(uint2*)(p + 4) = make_uint2(v.z, v.w);
}
// permlane swaps (gfx950) — P C-layout -> A-layout redistribution (verified r2)
static __device__ __forceinline__ void pl32swap(unsigned &a, unsigned &b) {
    auto r = __builtin_amdgcn_permlane32_swap(a, b, false, false);
    a = r[0]; b = r[1];
}
static __device__ __forceinline__ void pl16swap(unsigned &a, unsigned &b) {
    auto r = __builtin_amdgcn_permlane16_swap(a, b, false, false);
    a = r[0]; b = r[1];
}

#define MFMA16(a, b, c) __builtin_amdgcn_mfma_f32_16x16x32_bf16((a), (b), (c), 0, 0, 0)

// ---------------------------------------------------------------------------
// K0 (merged prep): [0,108): wqkv^T ; [108,144): wproj^T ; [144,912): x->bf16;
// [912,1936): bias zero-check -> flag (atomicOr of |bits|).
// ---------------------------------------------------------------------------
__global__ __launch_bounds__(256) void prep_kernel(
    const float* __restrict__ wqkv, const float* __restrict__ wproj,
    const float* __restrict__ x, const float* __restrict__ bias,
    u16* __restrict__ wqkvT, u16* __restrict__ wprojT,
    u16* __restrict__ xb, unsigned* __restrict__ flag)
{
    const int bid = blockIdx.x;
    const int t = threadIdx.x;
    if (bid >= 912) {   // bias nonzero check
        const float* gp = bias + (size_t)(bid - 912) * 4096 + (size_t)t * 16;
        unsigned acc = 0;
        #pragma unroll
        for (int u = 0; u < 4; ++u) {
            float4 v = *(const float4*)(gp + 4 * u);
            acc |= (__builtin_bit_cast(unsigned, v.x) & 0x7fffffffu);
            acc |= (__builtin_bit_cast(unsigned, v.y) & 0x7fffffffu);
            acc |= (__builtin_bit_cast(unsigned, v.z) & 0x7fffffffu);
            acc |= (__builtin_bit_cast(unsigned, v.w) & 0x7fffffffu);
        }
        if (acc) atomicOr(flag, 1u);
        return;
    }
    if (bid >= 144) {   // x -> bf16
        size_t base = (size_t)(bid - 144) * 4096 + (size_t)t * 16;
        const float* gp = x + base;
        __align__(16) u16 tmp[16];
        #pragma unroll
        for (int u = 0; u < 4; ++u) {
            float4 v = *(const float4*)(gp + 4 * u);
            tmp[4 * u + 0] = f2bu(v.x); tmp[4 * u + 1] = f2bu(v.y);
            tmp[4 * u + 2] = f2bu(v.z); tmp[4 * u + 3] = f2bu(v.w);
        }
        *(uint4*)(xb + base)     = *(const uint4*)tmp;
        *(uint4*)(xb + base + 8) = *(const uint4*)(tmp + 8);
        return;
    }
    const float* in; u16* out; int K, C, c0, k0;
    if (bid < 108) { in = wqkv;  out = wqkvT;  K = DDIM; C = QKVC;
                     c0 = (bid % 18) * 64; k0 = (bid / 18) * 64; }
    else           { int b2 = bid - 108; in = wproj; out = wprojT; K = DDIM; C = DDIM;
                     c0 = (b2 % 6) * 64; k0 = (b2 / 6) * 64; }
    __shared__ float tr[64][65];
    {
        int kr = t >> 2, cb = (t & 3) * 16;
        const float* gp = in + (size_t)(k0 + kr) * C + c0 + cb;
        #pragma unroll
        for (int u = 0; u < 4; ++u) {
            float4 v = *(const float4*)(gp + 4 * u);
            tr[cb + 4 * u + 0][kr] = v.x;
            tr[cb + 4 * u + 1][kr] = v.y;
            tr[cb + 4 * u + 2][kr] = v.z;
            tr[cb + 4 * u + 3][kr] = v.w;
        }
    }
    __syncthreads();
    {
        int c = t >> 2, kb = (t & 3) * 16;
        __align__(16) u16 tmp[16];
        #pragma unroll
        for (int u = 0; u < 16; ++u) tmp[u] = f2bu(tr[c][kb + u]);
        u16* op = out + (size_t)(c0 + c) * K + k0 + kb;
        *(uint4*)op       = *(const uint4*)tmp;
        *(uint4*)(op + 8) = *(const uint4*)(tmp + 8);
    }
}

// ---------------------------------------------------------------------------
// K1: qkv = xb @ wqkvT, RoPE fused (LDS ping-pong — r5-verified best config).
// Q pre-scaled by 0.125*log2e -> attn exp is exp2(s).
// ---------------------------------------------------------------------------
__global__ __launch_bounds__(256, 4) void qkv_rope_kernel(
    const u16* __restrict__ xb, const u16* __restrict__ wt,
    const float* __restrict__ cs, const float* __restrict__ sn,
    u16* __restrict__ qb, u16* __restrict__ kb, u16* __restrict__ vtb)
{
    __shared__ __align__(16) u16 xs[2][64][68];
    __shared__ __align__(16) u16 ws[2][64][68];
    const int t = threadIdx.x;
    const int wv = t >> 6, lane = t & 63, quad = lane >> 4, lo = lane & 15;
    const int r0 = blockIdx.y * 64;
    const int c0 = blockIdx.x * 64;
    const int sr = t >> 3, sd = (t & 7) * 8;

    st8(&xs[0][sr][sd],      *(const uint4*)(xb + (size_t)(r0 + sr) * DDIM + sd));
    st8(&xs[0][sr + 32][sd], *(const uint4*)(xb + (size_t)(r0 + sr + 32) * DDIM + sd));
    st8(&ws[0][sr][sd],      *(const uint4*)(wt + (size_t)(c0 + sr) * DDIM + sd));
    st8(&ws[0][sr + 32][sd], *(const uint4*)(wt + (size_t)(c0 + sr + 32) * DDIM + sd));
    __syncthreads();

    float4v acc[4] = {};
    for (int kk = 0; kk < 6; ++kk) {
        const int cur = kk & 1, nxt = cur ^ 1;
        const int kkn = (kk < 5 ? kk + 1 : 5) * 64;
        uint4 xp0 = *(const uint4*)(xb + (size_t)(r0 + sr) * DDIM + kkn + sd);
        uint4 xp1 = *(const uint4*)(xb + (size_t)(r0 + sr + 32) * DDIM + kkn + sd);
        uint4 wp0 = *(const uint4*)(wt + (size_t)(c0 + sr) * DDIM + kkn + sd);
        uint4 wp1 = *(const uint4*)(wt + (size_t)(c0 + sr + 32) * DDIM + kkn + sd);

        #pragma unroll
        for (int kf = 0; kf < 2; ++kf) {
            short8v a = ld_frag(&xs[cur][16 * wv + lo][kf * 32 + quad * 8]);
            #pragma unroll
            for (int nt = 0; nt < 4; ++nt) {
                short8v b = ld_frag(&ws[cur][nt * 16 + lo][kf * 32 + quad * 8]);
                acc[nt] = MFMA16(a, b, acc[nt]);
            }
        }
        st8(&xs[nxt][sr][sd], xp0);
        st8(&xs[nxt][sr + 32][sd], xp1);
        st8(&ws[nxt][sr][sd], wp0);
        st8(&ws[nxt][sr + 32][sd], wp1);
        __syncthreads();
    }

    const int sec = blockIdx.x / 6;     // 0=q, 1=k, 2=v
    const int h   = blockIdx.x % 6;
    const int rbase = r0 + 16 * wv + 4 * quad;
    const int bidx  = r0 >> 11;
    const int tbase = rbase & (TT - 1);

    if (sec == 2) {
        #pragma unroll
        for (int nt = 0; nt < 4; ++nt) {
            int d = nt * 16 + lo;
            unsigned a0 = pk2(acc[nt][0], acc[nt][1]);
            unsigned a1 = pk2(acc[nt][2], acc[nt][3]);
            u16* gp = vtb + ((size_t)(bidx * HH + h) * HD + d) * TT + tbase;
            *(uint2*)gp = make_uint2(a0, a1);
        }
    } else {
        u16* dst = (sec == 0) ? qb : kb;
        const float scl = (sec == 0) ? QSCALE : 1.0f;
        #pragma unroll
        for (int np = 0; np < 2; ++np) {
            #pragma unroll
            for (int r = 0; r < 4; ++r) {
                int tpos = tbase + r;
                int ci = np * 16 + lo;
                float cv = cs[tpos * 32 + ci];
                float sv = sn[tpos * 32 + ci];
                float x1 = acc[np][r], x2 = acc[np + 2][r];
                u16* gp = dst + ((size_t)(bidx * HH + h) * TT + tpos) * HD;
                gp[ci]      = f2bu((x1 * cv - x2 * sv) * scl);
                gp[ci + 32] = f2bu((x2 * cv + x1 * sv) * scl);
            }
        }
    }
}

// ---------------------------------------------------------------------------
// K2a: K-SPLIT flash attention (bias==0 fast path), r10 PHASE-SPLIT:
//  Per j-tile: Phase A = all 4 g's {S-MFMA, exp, pack} -> pa[4][2] (kq dead)
//  -> K reload (covered by PV + next-j VALU); Phase B = 32-MFMA PV cluster
//  under s_setprio(1) -> V reload (covered by next-j's whole S phase).
//  (r5's per-g reloads only had ~1 g-tail of latency cover.)
// ---------------------------------------------------------------------------
__global__ __launch_bounds__(256, 2) void attn_ksplit_kernel(
    const u16* __restrict__ qb, const u16* __restrict__ kb, const u16* __restrict__ vtb,
    const unsigned* __restrict__ flag, u16* __restrict__ ob)
{
    if (*flag != 0u) return;              // nonzero bias -> fallback kernel

    __shared__ __align__(16) float red_o[2][64][68];  // 34816 B (lane stride 68)
    __shared__ float red_l[4][64];

    const int t = threadIdx.x;
    const int wv = t >> 6, lane = t & 63, quad = lane >> 4, lo = lane & 15;
    const int bh = blockIdx.x;            // bh fastest: XCD = bh % 8
    const int b = bh / HH, h = bh % HH;
    const int q0 = blockIdx.y * 64;

    short8v aq[4][2];
    #pragma unroll
    for (int g = 0; g < 4; ++g) {
        const u16* qp = qb + ((size_t)bh * TT + q0 + g * 16 + lo) * HD + quad * 8;
        aq[g][0] = frag4(*(const uint4*)qp);
        aq[g][1] = frag4(*(const uint4*)(qp + 32));
    }

    const u16* kbase = kb + ((size_t)bh * TT + lo) * HD + quad * 8;
    const u16* vbase = vtb + ((size_t)bh * HD + lo) * TT + quad * 8;

    uint4 kq[4][2], vq[4][2];
    {
        const size_t ko = (size_t)wv * 64 * HD;
        const size_t vo = (size_t)wv * 64;
        #pragma unroll
        for (int nt = 0; nt < 4; ++nt) {
            kq[nt][0] = *(const uint4*)(kbase + ko + (size_t)nt * 16 * HD);
            kq[nt][1] = *(const uint4*)(kbase + ko + (size_t)nt * 16 * HD + 32);
        }
        #pragma unroll
        for (int dt = 0; dt < 4; ++dt) {
            vq[dt][0] = *(const uint4*)(vbase + (size_t)dt * 16 * TT + vo);
            vq[dt][1] = *(const uint4*)(vbase + (size_t)dt * 16 * TT + vo + 32);
        }
    }

    float4v oacc[4][4] = {};              // [g][dt]
    float lacc[4] = {0.f, 0.f, 0.f, 0.f};

    for (int j = 0; j < 8; ++j) {
        const int ktn = (j < 7) ? (wv + 4 * (j + 1)) : wv;
        const size_t kno = (size_t)ktn * 64 * HD;
        const size_t vno = (size_t)ktn * 64;

        // ---- Phase A: S^T + softmax + pack for ALL g (consumes kq) ----
        uint4 pa[4][2];
        #pragma unroll
        for (int g = 0; g < 4; ++g) {
            float4v s[4] = {};
            #pragma unroll
            for (int nt = 0; nt < 4; ++nt)
                s[nt] = MFMA16(frag4(kq[nt][0]), aq[g][0], s[nt]);
            #pragma unroll
            for (int nt = 0; nt < 4; ++nt)
                s[nt] = MFMA16(frag4(kq[nt][1]), aq[g][1], s[nt]);

            unsigned w[8];
            #pragma unroll
            for (int nt = 0; nt < 4; ++nt) {
                float p0 = __builtin_amdgcn_exp2f(s[nt][0]);
                float p1 = __builtin_amdgcn_exp2f(s[nt][1]);
                float p2 = __builtin_amdgcn_exp2f(s[nt][2]);
                float p3 = __builtin_amdgcn_exp2f(s[nt][3]);
                lacc[g] += (p0 + p1) + (p2 + p3);
                w[2 * nt]     = pk2(p0, p1);
                w[2 * nt + 1] = pk2(p2, p3);
            }
            pl32swap(w[0], w[2]); pl16swap(w[0], w[2]);
            pl32swap(w[1], w[3]); pl16swap(w[1], w[3]);
            pl32swap(w[4], w[6]); pl16swap(w[4], w[6]);
            pl32swap(w[5], w[7]); pl16swap(w[5], w[7]);
            pa[g][0] = make_uint4(w[0], w[1], w[2], w[3]);
            pa[g][1] = make_uint4(w[4], w[5], w[6], w[7]);
        }

        // K reload: kq dead; PV block + next-j S-VALU covers the L2 latency
        #pragma unroll
        for (int nt = 0; nt < 4; ++nt) {
            kq[nt][0] = *(const uint4*)(kbase + kno + (size_t)nt * 16 * HD);
            kq[nt][1] = *(const uint4*)(kbase + kno + (size_t)nt * 16 * HD + 32);
        }

        // ---- Phase B: PV for ALL g — one 32-MFMA cluster (T5 role-split) ----
        __builtin_amdgcn_s_setprio(1);
        #pragma unroll
        for (int g = 0; g < 4; ++g) {
            #pragma unroll
            for (int dt = 0; dt < 4; ++dt)
                oacc[g][dt] = MFMA16(frag4(pa[g][0]), frag4(vq[dt][0]), oacc[g][dt]);
            #pragma unroll
            for (int dt = 0; dt < 4; ++dt)
                oacc[g][dt] = MFMA16(frag4(pa[g][1]), frag4(vq[dt][1]), oacc[g][dt]);
        }
        __builtin_amdgcn_s_setprio(0);

        // V reload: vq dead; next-j's whole S phase covers the latency
        #pragma unroll
        for (int dt = 0; dt < 4; ++dt) {
            vq[dt][0] = *(const uint4*)(vbase + (size_t)dt * 16 * TT + vno);
            vq[dt][1] = *(const uint4*)(vbase + (size_t)dt * 16 * TT + vno + 32);
        }
    }

    #pragma unroll
    for (int g = 0; g < 4; ++g) {
        lacc[g] += __shfl_xor(lacc[g], 16);
        lacc[g] += __shfl_xor(lacc[g], 32);
    }
    if (quad == 0) {
        #pragma unroll
        for (int g = 0; g < 4; ++g) red_l[wv][g * 16 + lo] = lacc[g];
    }
    float* slot0 = &red_o[0][0][0] + (size_t)lane * 68;
    float* slot1 = &red_o[1][0][0] + (size_t)lane * 68;
    if (wv == 1 || wv == 3) {
        float* sp = (wv == 1) ? slot0 : slot1;
        #pragma unroll
        for (int g = 0; g < 4; ++g)
            #pragma unroll
            for (int dt = 0; dt < 4; ++dt)
                *(float4v*)(sp + (g * 4 + dt) * 4) = oacc[g][dt];
    }
    __syncthreads();
    if (wv == 0 || wv == 2) {
        float* sp = (wv == 0) ? slot0 : slot1;
        #pragma unroll
        for (int g = 0; g < 4; ++g)
            #pragma unroll
            for (int dt = 0; dt < 4; ++dt)
                oacc[g][dt] += *(const float4v*)(sp + (g * 4 + dt) * 4);
    }
    __syncthreads();
    if (wv == 2) {
        #pragma unroll
        for (int g = 0; g < 4; ++g)
            #pragma unroll
            for (int dt = 0; dt < 4; ++dt)
                *(float4v*)(slot1 + (g * 4 + dt) * 4) = oacc[g][dt];
    }
    __syncthreads();
    if (wv == 0) {
        #pragma unroll
        for (int g = 0; g < 4; ++g) {
            #pragma unroll
            for (int dt = 0; dt < 4; ++dt)
                oacc[g][dt] += *(const float4v*)(slot1 + (g * 4 + dt) * 4);
            float lt = red_l[0][g * 16 + lo] + red_l[1][g * 16 + lo]
                     + red_l[2][g * 16 + lo] + red_l[3][g * 16 + lo];
            #pragma unroll
            for (int r = 0; r < 4; ++r) {
                float lr = __shfl(lt, 4 * quad + r);
                float inv = 1.f / lr;
                u16* gp = ob + ((size_t)b * TT + q0 + g * 16 + 4 * quad + r) * DDIM
                             + h * HD + lo;
                #pragma unroll
                for (int dt = 0; dt < 4; ++dt)
                    gp[dt * 16] = f2bu(oacc[g][dt][r] * inv);
            }
        }
    }
}

// ---------------------------------------------------------------------------
// K2b: bias-nonzero fallback (proven LDS-staged loop, f32 bias). Early-exits
// when flag==0.
// ---------------------------------------------------------------------------
__global__ __launch_bounds__(256, 4) void attn_bias_kernel(
    const u16* __restrict__ qb, const u16* __restrict__ kb, const u16* __restrict__ vtb,
    const float* __restrict__ bias, const unsigned* __restrict__ flag,
    u16* __restrict__ ob)
{
    if (*flag == 0u) return;

    __shared__ __align__(16) u16 ks[2][64][68];
    __shared__ __align__(16) u16 vt[2][64][68];

    const int t = threadIdx.x;
    const int wv = t >> 6, lane = t & 63, quad = lane >> 4, lo = lane & 15;
    const int bh = blockIdx.x;
    const int b = bh / HH, h = bh % HH;
    const int q0 = blockIdx.y * 64;
    const int qrow = q0 + 16 * wv + lo;

    const u16* qbase = qb + ((size_t)bh * TT + qrow) * HD + quad * 8;
    short8v aq0 = frag4(*(const uint4*)qbase);
    short8v aq1 = frag4(*(const uint4*)(qbase + 32));

    const int sr = t >> 3, sd = (t & 7) * 8;
    const u16* kbbase = kb + (size_t)bh * TT * HD;
    const u16* vtbase = vtb + (size_t)bh * HD * TT;
    const float* brow = bias + (size_t)qrow * TT + 4 * quad;

    st8(&ks[0][sr][sd],      *(const uint4*)(kbbase + (size_t)sr * HD + sd));
    st8(&ks[0][sr + 32][sd], *(const uint4*)(kbbase + (size_t)(sr + 32) * HD + sd));
    st8(&vt[0][sr][sd],      *(const uint4*)(vtbase + (size_t)sr * TT + sd));
    st8(&vt[0][sr + 32][sd], *(const uint4*)(vtbase + (size_t)(sr + 32) * TT + sd));
    float4 bcur[4];
    #pragma unroll
    for (int nt = 0; nt < 4; ++nt) bcur[nt] = *(const float4*)(brow + nt * 16);
    __syncthreads();

    float4v oacc[4] = {};
    float lacc[4] = {0.f, 0.f, 0.f, 0.f};

    for (int kt = 0; kt < TT / 64; ++kt) {
        const int cur = kt & 1, nxt = cur ^ 1;
        const int kn = (kt < 31 ? kt + 1 : 31) * 64;

        uint4 kp0 = *(const uint4*)(kbbase + (size_t)(kn + sr) * HD + sd);
        uint4 kp1 = *(const uint4*)(kbbase + (size_t)(kn + sr + 32) * HD + sd);
        uint4 vp0 = *(const uint4*)(vtbase + (size_t)sr * TT + kn + sd);
        uint4 vp1 = *(const uint4*)(vtbase + (size_t)(sr + 32) * TT + kn + sd);
        float4 bnxt[4];
        #pragma unroll
        for (int nt = 0; nt < 4; ++nt) bnxt[nt] = *(const float4*)(brow + kn + nt * 16);

        float4v s[4] = {};
        #pragma unroll
        for (int kf = 0; kf < 2; ++kf) {
            #pragma unroll
            for (int nt = 0; nt < 4; ++nt) {
                short8v kfr = ld_frag(&ks[cur][nt * 16 + lo][kf * 32 + quad * 8]);
                s[nt] = MFMA16(kfr, (kf ? aq1 : aq0), s[nt]);
            }
        }

        unsigned w[8];
        #pragma unroll
        for (int nt = 0; nt < 4; ++nt) {
            float p0 = __builtin_amdgcn_exp2f(fmaf(bcur[nt].x, LOG2E, s[nt][0]));
            float p1 = __builtin_amdgcn_exp2f(fmaf(bcur[nt].y, LOG2E, s[nt][1]));
            float p2 = __builtin_amdgcn_exp2f(fmaf(bcur[nt].z, LOG2E, s[nt][2]));
            float p3 = __builtin_amdgcn_exp2f(fmaf(bcur[nt].w, LOG2E, s[nt][3]));
            lacc[nt] += (p0 + p1) + (p2 + p3);
            w[2 * nt]     = pk2(p0, p1);
            w[2 * nt + 1] = pk2(p2, p3);
        }

        pl32swap(w[0], w[2]); pl16swap(w[0], w[2]);
        pl32swap(w[1], w[3]); pl16swap(w[1], w[3]);
        pl32swap(w[4], w[6]); pl16swap(w[4], w[6]);
        pl32swap(w[5], w[7]); pl16swap(w[5], w[7]);
        short8v pa0 = frag4(make_uint4(w[0], w[1], w[2], w[3]));
        short8v pa1 = frag4(make_uint4(w[4], w[5], w[6], w[7]));

        #pragma unroll
        for (int kf = 0; kf < 2; ++kf) {
            #pragma unroll
            for (int dt = 0; dt < 4; ++dt) {
                short8v bv = ld_frag(&vt[cur][dt * 16 + lo][kf * 32 + quad * 8]);
                oacc[dt] = MFMA16((kf ? pa1 : pa0), bv, oacc[dt]);
            }
        }

        st8(&ks[nxt][sr][sd], kp0);
        st8(&ks[nxt][sr + 32][sd], kp1);
        st8(&vt[nxt][sr][sd], vp0);
        st8(&vt[nxt][sr + 32][sd], vp1);
        #pragma unroll
        for (int nt = 0; nt < 4; ++nt) bcur[nt] = bnxt[nt];
        __syncthreads();
    }

    float l = (lacc[0] + lacc[1]) + (lacc[2] + lacc[3]);
    l += __shfl_xor(l, 16);
    l += __shfl_xor(l, 32);
    #pragma unroll
    for (int r = 0; r < 4; ++r) {
        float lr = __shfl(l, 4 * quad + r);
        float inv = 1.f / lr;
        u16* gp = ob + ((size_t)b * TT + q0 + 16 * wv + 4 * quad + r) * DDIM + h * HD + lo;
        #pragma unroll
        for (int dt = 0; dt < 4; ++dt)
            gp[dt * 16] = f2bu(oacc[dt][r] * inv);
    }
}

// ---------------------------------------------------------------------------
// K3: out = O @ w_proj (MFMA), f32 output. Ping-pong (r5-verified).
// ---------------------------------------------------------------------------
__global__ __launch_bounds__(256, 4) void proj_kernel(
    const u16* __restrict__ o, const u16* __restrict__ wt, float* __restrict__ out)
{
    __shared__ __align__(16) u16 os[2][64][68];
    __shared__ __align__(16) u16 ws[2][64][68];
    const int t = threadIdx.x;
    const int wv = t >> 6, lane = t & 63, quad = lane >> 4, lo = lane & 15;
    const int r0 = blockIdx.y * 64, c0 = blockIdx.x * 64;
    const int sr = t >> 3, sd = (t & 7) * 8;

    st8(&os[0][sr][sd],      *(const uint4*)(o + (size_t)(r0 + sr) * DDIM + sd));
    st8(&os[0][sr + 32][sd], *(const uint4*)(o + (size_t)(r0 + sr + 32) * DDIM + sd));
    st8(&ws[0][sr][sd],      *(const uint4*)(wt + (size_t)(c0 + sr) * DDIM + sd));
    st8(&ws[0][sr + 32][sd], *(const uint4*)(wt + (size_t)(c0 + sr + 32) * DDIM + sd));
    __syncthreads();

    float4v acc[4] = {};
    for (int kk = 0; kk < 6; ++kk) {
        const int cur = kk & 1, nxt = cur ^ 1;
        const int kkn = (kk < 5 ? kk + 1 : 5) * 64;
        uint4 op0 = *(const uint4*)(o + (size_t)(r0 + sr) * DDIM + kkn + sd);
        uint4 op1 = *(const uint4*)(o + (size_t)(r0 + sr + 32) * DDIM + kkn + sd);
        uint4 wp0 = *(const uint4*)(wt + (size_t)(c0 + sr) * DDIM + kkn + sd);
        uint4 wp1 = *(const uint4*)(wt + (size_t)(c0 + sr + 32) * DDIM + kkn + sd);

        #pragma unroll
        for (int kf = 0; kf < 2; ++kf) {
            short8v a = ld_frag(&os[cur][16 * wv + lo][kf * 32 + quad * 8]);
            #pragma unroll
            for (int nt = 0; nt < 4; ++nt) {
                short8v bfr = ld_frag(&ws[cur][nt * 16 + lo][kf * 32 + quad * 8]);
                acc[nt] = MFMA16(a, bfr, acc[nt]);
            }
        }
        st8(&os[nxt][sr][sd], op0);
        st8(&os[nxt][sr + 32][sd], op1);
        st8(&ws[nxt][sr][sd], wp0);
        st8(&ws[nxt][sr + 32][sd], wp1);
        __syncthreads();
    }
    #pragma unroll
    for (int r = 0; r < 4; ++r) {
        float* gp = out + (size_t)(r0 + 16 * wv + 4 * quad + r) * DDIM + c0;
        #pragma unroll
        for (int nt = 0; nt < 4; ++nt)
            gp[nt * 16 + lo] = acc[nt][r];
    }
}

extern "C" void kernel_launch(void* const* d_in, const int* in_sizes, int n_in,
                              void* d_out, int out_size, void* d_ws, size_t ws_size,
                              hipStream_t stream) {
    const float* x     = (const float*)d_in[0];
    const float* bias  = (const float*)d_in[1];
    const float* cs    = (const float*)d_in[2];
    const float* sn    = (const float*)d_in[3];
    const float* wqkv  = (const float*)d_in[4];
    const float* wproj = (const float*)d_in[5];
    float* out = (float*)d_out;

    u16* wqkvT  = (u16*)d_ws;                         // [1152][384]
    u16* wprojT = wqkvT + (size_t)QKVC * DDIM;        // [384][384]
    u16* qb     = wprojT + (size_t)DDIM * DDIM;       // [bh][t][d]
    u16* kb     = qb + (size_t)BB * HH * TT * HD;     // [bh][t][d]
    u16* vtb    = kb + (size_t)BB * HH * TT * HD;     // [bh][d][t]
    u16* ob     = vtb + (size_t)BB * HH * TT * HD;    // [b][t][h*64+d]
    u16* xb     = ob + (size_t)BT * DDIM;             // [b*t][384] bf16 x
    unsigned* flag = (unsigned*)(xb + (size_t)BT * DDIM);

    hipMemsetAsync(flag, 0, sizeof(unsigned), stream);
    prep_kernel<<<dim3(144 + BT * DDIM / 4096 + TT * TT / 4096), 256, 0, stream>>>(
        wqkv, wproj, x, bias, wqkvT, wprojT, xb, flag);
    qkv_rope_kernel<<<dim3(QKVC / 64, BT / 64), 256, 0, stream>>>(
        xb, wqkvT, cs, sn, qb, kb, vtb);
    attn_ksplit_kernel<<<dim3(BB * HH, TT / 64), 256, 0, stream>>>(
        qb, kb, vtb, flag, ob);
    attn_bias_kernel<<<dim3(BB * HH, TT / 64), 256, 0, stream>>>(
        qb, kb, vtb, bias, flag, ob);
    proj_kernel<<<dim3(DDIM / 64, BT / 64), 256, 0, stream>>>(ob, wprojT, out);
}